// Round 3
// baseline (671.201 us; speedup 1.0000x reference)
//
#include <hip/hip_runtime.h>
#include <hip/hip_bf16.h>

// Problem constants
#define F 1024
#define N 64
#define C 256
#define HID 1024
#define NH 8
#define D 128

using bf16x8 = __attribute__((ext_vector_type(8))) short;
using u16x8  = __attribute__((ext_vector_type(8))) unsigned short;
using u16x4  = __attribute__((ext_vector_type(4))) unsigned short;
using f32x4  = __attribute__((ext_vector_type(4))) float;

__device__ __forceinline__ unsigned short f2b(float f) {
    union { float f; unsigned u; } v; v.f = f;
    unsigned u = v.u;
    unsigned r = (u + 0x7fffu + ((u >> 16) & 1u)) >> 16;  // RNE
    return (unsigned short)r;
}
__device__ __forceinline__ float b2f(unsigned short h) {
    union { unsigned u; float f; } v; v.u = ((unsigned)h) << 16;
    return v.f;
}

__device__ __forceinline__ void load_lds16(const unsigned short* g, unsigned short* l) {
    __builtin_amdgcn_global_load_lds(
        (const __attribute__((address_space(1))) void*)g,
        (__attribute__((address_space(3))) void*)l, 16, 0, 0);
}

// ---- Kernel 0z: zero the f32 accumulators (no hipMemsetAsync in capture) --
__global__ void k_zero(float* __restrict__ p) {
    int i = (blockIdx.x * 256 + threadIdx.x) * 4;
    float4 z; z.x = 0.f; z.y = 0.f; z.z = 0.f; z.w = 0.f;
    *(float4*)(p + i) = z;
}

// ---- Kernel 0a: x (f,n,c) fp32 -> xt (n,f,c) bf16 ------------------------
__global__ void k_conv_x(const float* __restrict__ x, unsigned short* __restrict__ xt) {
    int row = blockIdx.x * 4 + (threadIdx.x >> 6);  // input row index over (f,n)
    int lane = threadIdx.x & 63;
    int fi = row >> 6, ni = row & 63;
    float4 a = *(const float4*)(x + row * C + lane * 4);
    u16x4 o;
    o[0] = f2b(a.x); o[1] = f2b(a.y); o[2] = f2b(a.z); o[3] = f2b(a.w);
    *(u16x4*)(xt + (ni * F + fi) * C + lane * 4) = o;
}

// ---- Kernel 0b: W (c,hid) fp32 -> Wt[w][hid][c] bf16 (transposed) --------
__global__ void k_conv_w(const float* __restrict__ Wq, const float* __restrict__ Wk,
                         const float* __restrict__ Wv, unsigned short* __restrict__ Wt) {
    int w = blockIdx.z;
    const float* W = (w == 0) ? Wq : ((w == 1) ? Wk : Wv);
    unsigned short* O = Wt + w * (HID * C);
    int n0 = blockIdx.x * 64, k0 = blockIdx.y * 64;
    __shared__ float t[64][65];
    int tx = threadIdx.x & 63, ty = threadIdx.x >> 6;
#pragma unroll
    for (int i = 0; i < 16; i++) {
        int kl = ty + i * 4;
        t[kl][tx] = W[(k0 + kl) * HID + n0 + tx];
    }
    __syncthreads();
#pragma unroll
    for (int i = 0; i < 16; i++) {
        int nl = ty + i * 4;
        O[(n0 + nl) * C + k0 + tx] = f2b(t[tx][nl]);
    }
}

// ---- Phase 1: fused K/V projection + partial KV + Ksum -------------------
// One block per (n,h,ft): 128-frame chunk. Proj-K -> Ks, proj-V -> Vs
// (swizzled LDS), then acc2 = V^T K for this chunk, atomicAdd f32 into
// KV32/Ksum. Accumulator lifetimes sequential (no spill); 4096 blocks give
// 8-deep queue slack per CU slot.
__global__ __launch_bounds__(256, 2) void k_kv_fused(
    const unsigned short* __restrict__ xt, const unsigned short* __restrict__ Wt,
    const float* __restrict__ bk, const float* __restrict__ bv,
    float* __restrict__ KV32, float* __restrict__ Ksum) {
    __shared__ unsigned short Ks[128 * 128];  // 32768 B, swizzled
    __shared__ unsigned short Vs[128 * 128];  // 32768 B, swizzled
    __shared__ unsigned short Sx[128 * 32];   // 8192 B staging (x)
    __shared__ unsigned short Sw[128 * 32];   // 8192 B staging (W)
    // total 81920 B -> 2 blocks/CU

    // decode so all 8 heads of one joint land on the same XCD (x_n L2-hot)
    const int ni = blockIdx.x & 63, h = blockIdx.x >> 6;
    const int ft = blockIdx.y;
    const int b = ni * NH + h;
    const int tid = threadIdx.x, lane = tid & 63, w = tid >> 6;
    const int quad = lane >> 4, l15 = lane & 15;
    const int wm = w >> 1, wn = w & 1;
    const int srow = lane >> 2, scol = (lane & 3) * 8;

    const unsigned short* xrow = xt + (ni * F + ft * 128) * C;
    const unsigned short* Wkp = Wt + (HID * C) + (h * D) * C;
    const unsigned short* Wvp = Wt + 2 * (HID * C) + (h * D) * C;
    const float* bkp = bk + h * D;
    const float* bvp = bv + h * D;

#pragma unroll 1
    for (int pv = 0; pv < 2; pv++) {
        const unsigned short* Wp = pv ? Wvp : Wkp;
        f32x4 acc[4][4];
#pragma unroll
        for (int i = 0; i < 4; i++)
#pragma unroll
            for (int j = 0; j < 4; j++) acc[i][j] = (f32x4)0.f;
#pragma unroll
        for (int ks = 0; ks < 8; ks++) {
            const int kof = ks * 32;
            const unsigned short* ga = xrow + (w * 32 + srow) * C + kof + scol;
            const unsigned short* gw = Wp + (w * 32 + srow) * C + kof + scol;
            load_lds16(ga,          Sx + (w * 32) * 32);
            load_lds16(ga + 16 * C, Sx + (w * 32 + 16) * 32);
            load_lds16(gw,          Sw + (w * 32) * 32);
            load_lds16(gw + 16 * C, Sw + (w * 32 + 16) * 32);
            __syncthreads();
            bf16x8 af[4], bfr[4];
#pragma unroll
            for (int mb = 0; mb < 4; mb++)
                af[mb] = *(const bf16x8*)(Sw + (wm * 64 + mb * 16 + l15) * 32 + quad * 8);
#pragma unroll
            for (int nb = 0; nb < 4; nb++)
                bfr[nb] = *(const bf16x8*)(Sx + (wn * 64 + nb * 16 + l15) * 32 + quad * 8);
#pragma unroll
            for (int mb = 0; mb < 4; mb++)
#pragma unroll
                for (int nb = 0; nb < 4; nb++)
                    acc[mb][nb] = __builtin_amdgcn_mfma_f32_16x16x32_bf16(
                        af[mb], bfr[nb], acc[mb][nb], 0, 0, 0);
            __syncthreads();
        }
        // epilogue: C[dd][fi] -> bias (+elu for K), swizzled LDS store
        const float* bias = pv ? bvp : bkp;
        unsigned short* T = pv ? Vs : Ks;
#pragma unroll
        for (int mb = 0; mb < 4; mb++)
#pragma unroll
            for (int r = 0; r < 4; r++) {
                int dd = wm * 64 + mb * 16 + quad * 4 + r;
                float bb = bias[dd];
                char* rowp = (char*)T + dd * 256;
                int sw = (dd & 7) << 4;
#pragma unroll
                for (int nb = 0; nb < 4; nb++) {
                    int fi = wn * 64 + nb * 16 + l15;
                    float v = acc[mb][nb][r] + bb;
                    if (!pv) v = (v > 0.f) ? (v + 1.f) : __expf(v);
                    *(unsigned short*)(rowp + ((fi * 2) ^ sw)) = f2b(v);
                }
            }
        __syncthreads();
    }

    // KV accumulate over the 128 local frames: acc2[m][d] = V^T K
    f32x4 acc2[4][4];
#pragma unroll
    for (int i = 0; i < 4; i++)
#pragma unroll
        for (int j = 0; j < 4; j++) acc2[i][j] = (f32x4)0.f;
#pragma unroll
    for (int k0 = 0; k0 < 128; k0 += 32) {
        bf16x8 af[4], bfr[4];
#pragma unroll
        for (int mb = 0; mb < 4; mb++) {
            int m = wm * 64 + mb * 16 + l15;
            af[mb] = *(const bf16x8*)((const char*)Vs + m * 256 +
                                      (((k0 + quad * 8) * 2) ^ ((m & 7) << 4)));
        }
#pragma unroll
        for (int nb = 0; nb < 4; nb++) {
            int d = wn * 64 + nb * 16 + l15;
            bfr[nb] = *(const bf16x8*)((const char*)Ks + d * 256 +
                                       (((k0 + quad * 8) * 2) ^ ((d & 7) << 4)));
        }
#pragma unroll
        for (int mb = 0; mb < 4; mb++)
#pragma unroll
            for (int nb = 0; nb < 4; nb++)
                acc2[mb][nb] = __builtin_amdgcn_mfma_f32_16x16x32_bf16(
                    af[mb], bfr[nb], acc2[mb][nb], 0, 0, 0);
    }

    // Ksum partial from Ks rows (swizzle is a within-row permutation)
    float ksacc = 0.f;
    {
        const int zd = tid >> 1, zh = tid & 1;
        const char* kr = (const char*)Ks + zd * 256;
        int sw = (zd & 7) << 4;
#pragma unroll
        for (int c = 0; c < 8; c++) {
            u16x8 v = *(const u16x8*)(kr + (((zh * 8 + c) * 16) ^ sw));
#pragma unroll
            for (int j = 0; j < 8; j++) ksacc += b2f(v[j]);
        }
    }
    __syncthreads();
    float* sred = (float*)Sx;
    sred[tid] = ksacc;
    __syncthreads();
    if (tid < 128) atomicAdd(&Ksum[b * D + tid], sred[2 * tid] + sred[2 * tid + 1]);

    // atomic f32 accumulate KV partial
    float* KVp = KV32 + b * (D * D);
#pragma unroll
    for (int mb = 0; mb < 4; mb++)
#pragma unroll
        for (int r = 0; r < 4; r++) {
            int m = wm * 64 + mb * 16 + quad * 4 + r;
#pragma unroll
            for (int nb = 0; nb < 4; nb++) {
                int d = wn * 64 + nb * 16 + l15;
                atomicAdd(KVp + m * D + d, acc2[mb][nb][r]);
            }
        }
}

// ---- Kernel: KV f32 -> bf16 ----------------------------------------------
__global__ void k_conv_kv(const float* __restrict__ KV32, unsigned short* __restrict__ KVb) {
    int i = (blockIdx.x * 256 + threadIdx.x) * 8;
    float4 a = *(const float4*)(KV32 + i);
    float4 c = *(const float4*)(KV32 + i + 4);
    u16x8 o;
    o[0] = f2b(a.x); o[1] = f2b(a.y); o[2] = f2b(a.z); o[3] = f2b(a.w);
    o[4] = f2b(c.x); o[5] = f2b(c.y); o[6] = f2b(c.z); o[7] = f2b(c.w);
    *(u16x8*)(KVb + i) = o;
}

// ---- Phase 2: fused Q projection + Z + out GEMM --------------------------
__global__ __launch_bounds__(256, 3) void k_out_fused(
    const unsigned short* __restrict__ xt, const unsigned short* __restrict__ Wt,
    const float* __restrict__ bq, const unsigned short* __restrict__ KV,
    const float* __restrict__ Ksum, float* __restrict__ out) {
    __shared__ unsigned short Qs[128 * 128];  // 32768 B, swizzled
    __shared__ unsigned short Sx[128 * 32];   // 8192 B
    __shared__ unsigned short Sw[128 * 32];   // 8192 B
    __shared__ float Kss[128];
    __shared__ float Zs[128];
    // total 50176 B -> 3 blocks/CU

    const int ni = blockIdx.x & 63, h = blockIdx.x >> 6;
    const int b = ni * NH + h;
    const int l0 = blockIdx.y * 128;
    const int tid = threadIdx.x, lane = tid & 63, w = tid >> 6;
    const int quad = lane >> 4, l15 = lane & 15;
    const int wm = w >> 1, wn = w & 1;
    const int srow = lane >> 2, scol = (lane & 3) * 8;

    if (tid < 128) Kss[tid] = Ksum[b * D + tid];

    const unsigned short* xrow = xt + (ni * F + l0) * C;
    const unsigned short* Wqp = Wt + (h * D) * C;

    // Q projection (Q-mode): C[fi][dd]
    f32x4 acc[4][4];
#pragma unroll
    for (int i = 0; i < 4; i++)
#pragma unroll
        for (int j = 0; j < 4; j++) acc[i][j] = (f32x4)0.f;
#pragma unroll
    for (int ks = 0; ks < 8; ks++) {
        const int kof = ks * 32;
        const unsigned short* ga = xrow + (w * 32 + srow) * C + kof + scol;
        const unsigned short* gw = Wqp + (w * 32 + srow) * C + kof + scol;
        load_lds16(ga,          Sx + (w * 32) * 32);
        load_lds16(ga + 16 * C, Sx + (w * 32 + 16) * 32);
        load_lds16(gw,          Sw + (w * 32) * 32);
        load_lds16(gw + 16 * C, Sw + (w * 32 + 16) * 32);
        __syncthreads();
        bf16x8 af[4], bfr[4];
#pragma unroll
        for (int mb = 0; mb < 4; mb++)
            af[mb] = *(const bf16x8*)(Sx + (wm * 64 + mb * 16 + l15) * 32 + quad * 8);
#pragma unroll
        for (int nb = 0; nb < 4; nb++)
            bfr[nb] = *(const bf16x8*)(Sw + (wn * 64 + nb * 16 + l15) * 32 + quad * 8);
#pragma unroll
        for (int mb = 0; mb < 4; mb++)
#pragma unroll
            for (int nb = 0; nb < 4; nb++)
                acc[mb][nb] = __builtin_amdgcn_mfma_f32_16x16x32_bf16(
                    af[mb], bfr[nb], acc[mb][nb], 0, 0, 0);
        __syncthreads();
    }
    // epilogue: bias + elu+1, swizzled LDS store of Q[fi][dd]
    {
        float bcol[4];
#pragma unroll
        for (int nb = 0; nb < 4; nb++) bcol[nb] = bq[h * D + wn * 64 + nb * 16 + l15];
#pragma unroll
        for (int mb = 0; mb < 4; mb++)
#pragma unroll
            for (int r = 0; r < 4; r++) {
                int fi = wm * 64 + mb * 16 + quad * 4 + r;
                char* rowp = (char*)Qs + fi * 256;
                int sw = (fi & 7) << 4;
#pragma unroll
                for (int nb = 0; nb < 4; nb++) {
                    int dd = wn * 64 + nb * 16 + l15;
                    float v = acc[mb][nb][r] + bcol[nb];
                    v = (v > 0.f) ? (v + 1.f) : __expf(v);
                    *(unsigned short*)(rowp + ((dd * 2) ^ sw)) = f2b(v);
                }
            }
    }
    __syncthreads();
    // Z[l] = 1/(Q[l]·Ksum + eps)
    if (tid < 128) {
        const char* qr = (const char*)Qs + tid * 256;
        int sw = (tid & 7) << 4;
        float s = 0.f;
#pragma unroll
        for (int c = 0; c < 16; c++) {
            u16x8 v = *(const u16x8*)(qr + ((c * 16) ^ sw));
#pragma unroll
            for (int j = 0; j < 8; j++) s += b2f(v[j]) * Kss[c * 8 + j];
        }
        Zs[tid] = 1.f / (s + 1e-6f);
    }
    __syncthreads();
    // out GEMM: C[m][l] = sum_d KV[m][d] * Q[l][d]
    const unsigned short* KVp = KV + b * (D * D);
    f32x4 o4[4][4];
#pragma unroll
    for (int i = 0; i < 4; i++)
#pragma unroll
        for (int j = 0; j < 4; j++) o4[i][j] = (f32x4)0.f;
#pragma unroll
    for (int k0 = 0; k0 < 128; k0 += 32) {
        bf16x8 af[4], bfr[4];
#pragma unroll
        for (int mb = 0; mb < 4; mb++) {
            int m = wm * 64 + mb * 16 + l15;
            af[mb] = *(const bf16x8*)(KVp + m * D + k0 + quad * 8);
        }
#pragma unroll
        for (int nb = 0; nb < 4; nb++) {
            int l = wn * 64 + nb * 16 + l15;
            bfr[nb] = *(const bf16x8*)((const char*)Qs + l * 256 +
                                       (((k0 + quad * 8) * 2) ^ ((l & 7) << 4)));
        }
#pragma unroll
        for (int mb = 0; mb < 4; mb++)
#pragma unroll
            for (int nb = 0; nb < 4; nb++)
                o4[mb][nb] = __builtin_amdgcn_mfma_f32_16x16x32_bf16(
                    af[mb], bfr[nb], o4[mb][nb], 0, 0, 0);
    }
#pragma unroll
    for (int nb = 0; nb < 4; nb++) {
        int l = wn * 64 + nb * 16 + l15;
        float z = Zs[l];
        float* op = out + ((l0 + l) * N + ni) * HID + h * D;
#pragma unroll
        for (int mb = 0; mb < 4; mb++) {
            int m0 = wm * 64 + mb * 16 + quad * 4;
            float4 vv;
            vv.x = o4[mb][nb][0] * z;
            vv.y = o4[mb][nb][1] * z;
            vv.z = o4[mb][nb][2] * z;
            vv.w = o4[mb][nb][3] * z;
            *(float4*)(op + m0) = vv;
        }
    }
}

// ---- launch --------------------------------------------------------------
// ws layout (bytes):
//   xt   @ 0          : 33,554,432  ((n,f,c) bf16)
//   Wt   @ 33554432   :  1,572,864  (3*1024*256 bf16, transposed)
//   KVb  @ 35127296   : 16,777,216  ((n,h,m,d) bf16)
//   KV32 @ 51904512   : 33,554,432  ((n,h,m,d) f32, atomic accum)
//   Ksum @ 85458944   :    262,144  ((n,h,d) fp32, atomic accum)
extern "C" void kernel_launch(void* const* d_in, const int* in_sizes, int n_in,
                              void* d_out, int out_size, void* d_ws, size_t ws_size,
                              hipStream_t stream) {
    const float* x  = (const float*)d_in[0];
    const float* Wq = (const float*)d_in[1];
    const float* bq = (const float*)d_in[2];
    const float* Wk = (const float*)d_in[3];
    const float* bk = (const float*)d_in[4];
    const float* Wv = (const float*)d_in[5];
    const float* bv = (const float*)d_in[6];
    float* out = (float*)d_out;
    char* ws = (char*)d_ws;

    unsigned short* xt   = (unsigned short*)(ws);
    unsigned short* Wt   = (unsigned short*)(ws + 33554432);
    unsigned short* KVb  = (unsigned short*)(ws + 35127296);
    float*          KV32 = (float*)(ws + 51904512);
    float*          Ksum = (float*)(ws + 85458944);

    // zero KV32 + Ksum (contiguous: 33,554,432 + 262,144 = 33,816,576 B
    // = 8,454,144 floats = 8256 blocks x 256 threads x 4 floats)
    k_zero<<<8256, 256, 0, stream>>>(KV32);

    k_conv_x<<<16384, 256, 0, stream>>>(x, xt);
    k_conv_w<<<dim3(16, 4, 3), 256, 0, stream>>>(Wq, Wk, Wv, Wt);
    k_kv_fused<<<dim3(512, 8), 256, 0, stream>>>(xt, Wt, bk, bv, KV32, Ksum);
    k_conv_kv<<<4096, 256, 0, stream>>>(KV32, KVb);
    k_out_fused<<<dim3(512, 8), 256, 0, stream>>>(xt, Wt, bq, KVb, Ksum, out);
}

// Round 4
// 584.666 us; speedup vs baseline: 1.1480x; 1.1480x over previous
//
#include <hip/hip_runtime.h>
#include <hip/hip_bf16.h>

// Problem constants
#define F 1024
#define N 64
#define C 256
#define HID 1024
#define NH 8
#define D 128

using bf16x8 = __attribute__((ext_vector_type(8))) short;
using u16x8  = __attribute__((ext_vector_type(8))) unsigned short;
using u16x4  = __attribute__((ext_vector_type(4))) unsigned short;
using f32x4  = __attribute__((ext_vector_type(4))) float;

__device__ __forceinline__ unsigned short f2b(float f) {
    union { float f; unsigned u; } v; v.f = f;
    unsigned u = v.u;
    unsigned r = (u + 0x7fffu + ((u >> 16) & 1u)) >> 16;  // RNE
    return (unsigned short)r;
}
__device__ __forceinline__ float b2f(unsigned short h) {
    union { unsigned u; float f; } v; v.u = ((unsigned)h) << 16;
    return v.f;
}

__device__ __forceinline__ void load_lds16(const unsigned short* g, unsigned short* l) {
    __builtin_amdgcn_global_load_lds(
        (const __attribute__((address_space(1))) void*)g,
        (__attribute__((address_space(3))) void*)l, 16, 0, 0);
}

// ---- Kernel 0a: x (f,n,c) fp32 -> xt (n,f,c) bf16 ------------------------
__global__ void k_conv_x(const float* __restrict__ x, unsigned short* __restrict__ xt) {
    int row = blockIdx.x * 4 + (threadIdx.x >> 6);  // input row index over (f,n)
    int lane = threadIdx.x & 63;
    int fi = row >> 6, ni = row & 63;
    float4 a = *(const float4*)(x + row * C + lane * 4);
    u16x4 o;
    o[0] = f2b(a.x); o[1] = f2b(a.y); o[2] = f2b(a.z); o[3] = f2b(a.w);
    *(u16x4*)(xt + (ni * F + fi) * C + lane * 4) = o;
}

// ---- Kernel 0b: W (c,hid) fp32 -> Wt[w][hid][c] bf16 (transposed) --------
__global__ void k_conv_w(const float* __restrict__ Wq, const float* __restrict__ Wk,
                         const float* __restrict__ Wv, unsigned short* __restrict__ Wt) {
    int w = blockIdx.z;
    const float* W = (w == 0) ? Wq : ((w == 1) ? Wk : Wv);
    unsigned short* O = Wt + w * (HID * C);
    int n0 = blockIdx.x * 64, k0 = blockIdx.y * 64;
    __shared__ float t[64][65];
    int tx = threadIdx.x & 63, ty = threadIdx.x >> 6;
#pragma unroll
    for (int i = 0; i < 16; i++) {
        int kl = ty + i * 4;
        t[kl][tx] = W[(k0 + kl) * HID + n0 + tx];
    }
    __syncthreads();
#pragma unroll
    for (int i = 0; i < 16; i++) {
        int nl = ty + i * 4;
        O[(n0 + nl) * C + k0 + tx] = f2b(t[tx][nl]);
    }
}

// ---- Phase 1: fused K/V projection + KV + Ksum (512-thread, resident acc2)
// One block per (n,h), 8 waves. Per f-tile of 128 frames: T-mode proj K -> Ks,
// V -> Vs (swizzled LDS), then acc2[m][d] += V^T K.  acc2 is per-wave 64x32
// (32 VGPRs) so it stays resident across all 8 f-tiles without spill.
// KV/Ksum written once with plain stores; no atomics, no f32 scratch.
__global__ __launch_bounds__(512, 2) void k_kv_fused(
    const unsigned short* __restrict__ xt, const unsigned short* __restrict__ Wt,
    const float* __restrict__ bk, const float* __restrict__ bv,
    unsigned short* __restrict__ KVb, float* __restrict__ Ksum) {
    __shared__ unsigned short Ks[128 * 128];  // 32768 B, swizzled
    __shared__ unsigned short Vs[128 * 128];  // 32768 B, swizzled
    __shared__ unsigned short Sx[128 * 32];   // 8192 B staging (x)
    __shared__ unsigned short Sw[128 * 32];   // 8192 B staging (W)
    // total 81920 B

    // same-ni blocks are 64 apart -> same XCD -> x_n stays L2-hot
    const int ni = blockIdx.x & 63, h = blockIdx.x >> 6;
    const int b = ni * NH + h;
    const int tid = threadIdx.x, lane = tid & 63, w = tid >> 6;
    const int quad = lane >> 4, l15 = lane & 15;
    const int wm2 = w >> 2, wn2 = w & 3;          // 2m x 4n wave grid
    const int srow = w * 16 + (lane >> 2);        // staging row 0..127
    const int scol = (lane & 3) * 8;              // staging col (shorts)

    const unsigned short* xb  = xt + ni * (F * C);
    const unsigned short* Wkp = Wt + (HID * C) + (h * D) * C;
    const unsigned short* Wvp = Wt + 2 * (HID * C) + (h * D) * C;
    const float* bkp = bk + h * D;
    const float* bvp = bv + h * D;

    f32x4 acc2[4][2];
#pragma unroll
    for (int i = 0; i < 4; i++)
#pragma unroll
        for (int j = 0; j < 2; j++) acc2[i][j] = (f32x4)0.f;
    float ksacc = 0.f;
    const int zd = tid >> 2, zq = tid & 3;        // Ksum: 4 threads/row

#pragma unroll 1
    for (int ft = 0; ft < 8; ft++) {
        const unsigned short* xrow = xb + (ft * 128) * C;
#pragma unroll 1
        for (int pv = 0; pv < 2; pv++) {
            const unsigned short* Wp = pv ? Wvp : Wkp;
            f32x4 acc[4][2];
#pragma unroll
            for (int i = 0; i < 4; i++)
#pragma unroll
                for (int j = 0; j < 2; j++) acc[i][j] = (f32x4)0.f;
#pragma unroll
            for (int ks = 0; ks < 8; ks++) {
                const int kof = ks * 32;
                // one 16B load per lane covers the whole 128x32 tile (512 lanes)
                load_lds16(xrow + srow * C + kof + scol, Sx + (w * 16) * 32);
                load_lds16(Wp   + srow * C + kof + scol, Sw + (w * 16) * 32);
                __syncthreads();
                bf16x8 af[4], bfr[2];
#pragma unroll
                for (int mb = 0; mb < 4; mb++)
                    af[mb] = *(const bf16x8*)(Sw + (wm2 * 64 + mb * 16 + l15) * 32 + quad * 8);
#pragma unroll
                for (int nb = 0; nb < 2; nb++)
                    bfr[nb] = *(const bf16x8*)(Sx + (wn2 * 32 + nb * 16 + l15) * 32 + quad * 8);
#pragma unroll
                for (int mb = 0; mb < 4; mb++)
#pragma unroll
                    for (int nb = 0; nb < 2; nb++)
                        acc[mb][nb] = __builtin_amdgcn_mfma_f32_16x16x32_bf16(
                            af[mb], bfr[nb], acc[mb][nb], 0, 0, 0);
                __syncthreads();
            }
            // epilogue: C[dd][fi] -> bias (+elu for K), swizzled LDS store
            const float* bias = pv ? bvp : bkp;
            unsigned short* T = pv ? Vs : Ks;
#pragma unroll
            for (int mb = 0; mb < 4; mb++)
#pragma unroll
                for (int r = 0; r < 4; r++) {
                    int dd = wm2 * 64 + mb * 16 + quad * 4 + r;
                    float bb = bias[dd];
                    char* rowp = (char*)T + dd * 256;
                    int sw = (dd & 7) << 4;
#pragma unroll
                    for (int nb = 0; nb < 2; nb++) {
                        int fi = wn2 * 32 + nb * 16 + l15;
                        float v = acc[mb][nb][r] + bb;
                        if (!pv) v = (v > 0.f) ? (v + 1.f) : __expf(v);
                        *(unsigned short*)(rowp + ((fi * 2) ^ sw)) = f2b(v);
                    }
                }
            __syncthreads();
        }

        // KV accumulate over the 128 local frames: acc2[m][d] += V^T K
#pragma unroll
        for (int k0 = 0; k0 < 128; k0 += 32) {
            bf16x8 af[4], bfr[2];
#pragma unroll
            for (int mb = 0; mb < 4; mb++) {
                int m = wm2 * 64 + mb * 16 + l15;
                af[mb] = *(const bf16x8*)((const char*)Vs + m * 256 +
                                          (((k0 + quad * 8) * 2) ^ ((m & 7) << 4)));
            }
#pragma unroll
            for (int nb = 0; nb < 2; nb++) {
                int d = wn2 * 32 + nb * 16 + l15;
                bfr[nb] = *(const bf16x8*)((const char*)Ks + d * 256 +
                                           (((k0 + quad * 8) * 2) ^ ((d & 7) << 4)));
            }
#pragma unroll
            for (int mb = 0; mb < 4; mb++)
#pragma unroll
                for (int nb = 0; nb < 2; nb++)
                    acc2[mb][nb] = __builtin_amdgcn_mfma_f32_16x16x32_bf16(
                        af[mb], bfr[nb], acc2[mb][nb], 0, 0, 0);
        }

        // Ksum partial from Ks rows (swizzle is a within-row permutation);
        // 4 threads per d-row, 32 elements each
        {
            const char* kr = (const char*)Ks + zd * 256;
            int sw = (zd & 7) << 4;
#pragma unroll
            for (int c = 0; c < 4; c++) {
                u16x8 v = *(const u16x8*)(kr + ((zq * 64 + c * 16) ^ sw));
#pragma unroll
                for (int j = 0; j < 8; j++) ksacc += b2f(v[j]);
            }
        }
        // next f-tile's first staging barrier orders these LDS reads vs rewrites
    }

    // KV store: bf16, plain coalesced stores
    unsigned short* KVp = KVb + b * (D * D);
#pragma unroll
    for (int mb = 0; mb < 4; mb++)
#pragma unroll
        for (int r = 0; r < 4; r++) {
            int m = wm2 * 64 + mb * 16 + quad * 4 + r;
#pragma unroll
            for (int nb = 0; nb < 2; nb++) {
                int d = wn2 * 32 + nb * 16 + l15;
                KVp[m * D + d] = f2b(acc2[mb][nb][r]);
            }
        }

    // Ksum reduction: 4 partials per row
    __syncthreads();
    float* sred = (float*)Sx;   // 512 floats = 2048 B, fits
    sred[tid] = ksacc;
    __syncthreads();
    if (tid < 128)
        Ksum[b * D + tid] = sred[4 * tid] + sred[4 * tid + 1] +
                            sred[4 * tid + 2] + sred[4 * tid + 3];
}

// ---- Phase 2: fused Q projection + Z + out GEMM --------------------------
__global__ __launch_bounds__(256, 3) void k_out_fused(
    const unsigned short* __restrict__ xt, const unsigned short* __restrict__ Wt,
    const float* __restrict__ bq, const unsigned short* __restrict__ KV,
    const float* __restrict__ Ksum, float* __restrict__ out) {
    __shared__ unsigned short Qs[128 * 128];  // 32768 B, swizzled
    __shared__ unsigned short Sx[128 * 32];   // 8192 B
    __shared__ unsigned short Sw[128 * 32];   // 8192 B
    __shared__ float Kss[128];
    __shared__ float Zs[128];
    // total 50176 B -> 3 blocks/CU

    const int ni = blockIdx.x & 63, h = blockIdx.x >> 6;
    const int b = ni * NH + h;
    const int l0 = blockIdx.y * 128;
    const int tid = threadIdx.x, lane = tid & 63, w = tid >> 6;
    const int quad = lane >> 4, l15 = lane & 15;
    const int wm = w >> 1, wn = w & 1;
    const int srow = lane >> 2, scol = (lane & 3) * 8;

    if (tid < 128) Kss[tid] = Ksum[b * D + tid];

    const unsigned short* xrow = xt + (ni * F + l0) * C;
    const unsigned short* Wqp = Wt + (h * D) * C;

    // Q projection (Q-mode): C[fi][dd]
    f32x4 acc[4][4];
#pragma unroll
    for (int i = 0; i < 4; i++)
#pragma unroll
        for (int j = 0; j < 4; j++) acc[i][j] = (f32x4)0.f;
#pragma unroll
    for (int ks = 0; ks < 8; ks++) {
        const int kof = ks * 32;
        const unsigned short* ga = xrow + (w * 32 + srow) * C + kof + scol;
        const unsigned short* gw = Wqp + (w * 32 + srow) * C + kof + scol;
        load_lds16(ga,          Sx + (w * 32) * 32);
        load_lds16(ga + 16 * C, Sx + (w * 32 + 16) * 32);
        load_lds16(gw,          Sw + (w * 32) * 32);
        load_lds16(gw + 16 * C, Sw + (w * 32 + 16) * 32);
        __syncthreads();
        bf16x8 af[4], bfr[4];
#pragma unroll
        for (int mb = 0; mb < 4; mb++)
            af[mb] = *(const bf16x8*)(Sx + (wm * 64 + mb * 16 + l15) * 32 + quad * 8);
#pragma unroll
        for (int nb = 0; nb < 4; nb++)
            bfr[nb] = *(const bf16x8*)(Sw + (wn * 64 + nb * 16 + l15) * 32 + quad * 8);
#pragma unroll
        for (int mb = 0; mb < 4; mb++)
#pragma unroll
            for (int nb = 0; nb < 4; nb++)
                acc[mb][nb] = __builtin_amdgcn_mfma_f32_16x16x32_bf16(
                    af[mb], bfr[nb], acc[mb][nb], 0, 0, 0);
        __syncthreads();
    }
    // epilogue: bias + elu+1, swizzled LDS store of Q[fi][dd]
    {
        float bcol[4];
#pragma unroll
        for (int nb = 0; nb < 4; nb++) bcol[nb] = bq[h * D + wn * 64 + nb * 16 + l15];
#pragma unroll
        for (int mb = 0; mb < 4; mb++)
#pragma unroll
            for (int r = 0; r < 4; r++) {
                int fi = wm * 64 + mb * 16 + quad * 4 + r;
                char* rowp = (char*)Qs + fi * 256;
                int sw = (fi & 7) << 4;
#pragma unroll
                for (int nb = 0; nb < 4; nb++) {
                    int dd = wn * 64 + nb * 16 + l15;
                    float v = acc[mb][nb][r] + bcol[nb];
                    v = (v > 0.f) ? (v + 1.f) : __expf(v);
                    *(unsigned short*)(rowp + ((dd * 2) ^ sw)) = f2b(v);
                }
            }
    }
    __syncthreads();
    // Z[l] = 1/(Q[l]·Ksum + eps)
    if (tid < 128) {
        const char* qr = (const char*)Qs + tid * 256;
        int sw = (tid & 7) << 4;
        float s = 0.f;
#pragma unroll
        for (int c = 0; c < 16; c++) {
            u16x8 v = *(const u16x8*)(qr + ((c * 16) ^ sw));
#pragma unroll
            for (int j = 0; j < 8; j++) s += b2f(v[j]) * Kss[c * 8 + j];
        }
        Zs[tid] = 1.f / (s + 1e-6f);
    }
    __syncthreads();
    // out GEMM: C[m][l] = sum_d KV[m][d] * Q[l][d]
    const unsigned short* KVp = KV + b * (D * D);
    f32x4 o4[4][4];
#pragma unroll
    for (int i = 0; i < 4; i++)
#pragma unroll
        for (int j = 0; j < 4; j++) o4[i][j] = (f32x4)0.f;
#pragma unroll
    for (int k0 = 0; k0 < 128; k0 += 32) {
        bf16x8 af[4], bfr[4];
#pragma unroll
        for (int mb = 0; mb < 4; mb++) {
            int m = wm * 64 + mb * 16 + l15;
            af[mb] = *(const bf16x8*)(KVp + m * D + k0 + quad * 8);
        }
#pragma unroll
        for (int nb = 0; nb < 4; nb++) {
            int l = wn * 64 + nb * 16 + l15;
            bfr[nb] = *(const bf16x8*)((const char*)Qs + l * 256 +
                                       (((k0 + quad * 8) * 2) ^ ((l & 7) << 4)));
        }
#pragma unroll
        for (int mb = 0; mb < 4; mb++)
#pragma unroll
            for (int nb = 0; nb < 4; nb++)
                o4[mb][nb] = __builtin_amdgcn_mfma_f32_16x16x32_bf16(
                    af[mb], bfr[nb], o4[mb][nb], 0, 0, 0);
    }
#pragma unroll
    for (int nb = 0; nb < 4; nb++) {
        int l = wn * 64 + nb * 16 + l15;
        float z = Zs[l];
        float* op = out + ((l0 + l) * N + ni) * HID + h * D;
#pragma unroll
        for (int mb = 0; mb < 4; mb++) {
            int m0 = wm * 64 + mb * 16 + quad * 4;
            float4 vv;
            vv.x = o4[mb][nb][0] * z;
            vv.y = o4[mb][nb][1] * z;
            vv.z = o4[mb][nb][2] * z;
            vv.w = o4[mb][nb][3] * z;
            *(float4*)(op + m0) = vv;
        }
    }
}

// ---- launch --------------------------------------------------------------
// ws layout (bytes):
//   xt   @ 0          : 33,554,432  ((n,f,c) bf16)
//   Wt   @ 33554432   :  1,572,864  (3*1024*256 bf16, transposed)
//   KVb  @ 35127296   : 16,777,216  ((n,h,m,d) bf16)
//   Ksum @ 51904512   :    262,144  ((n,h,d) fp32)
extern "C" void kernel_launch(void* const* d_in, const int* in_sizes, int n_in,
                              void* d_out, int out_size, void* d_ws, size_t ws_size,
                              hipStream_t stream) {
    const float* x  = (const float*)d_in[0];
    const float* Wq = (const float*)d_in[1];
    const float* bq = (const float*)d_in[2];
    const float* Wk = (const float*)d_in[3];
    const float* bk = (const float*)d_in[4];
    const float* Wv = (const float*)d_in[5];
    const float* bv = (const float*)d_in[6];
    float* out = (float*)d_out;
    char* ws = (char*)d_ws;

    unsigned short* xt   = (unsigned short*)(ws);
    unsigned short* Wt   = (unsigned short*)(ws + 33554432);
    unsigned short* KVb  = (unsigned short*)(ws + 35127296);
    float*          Ksum = (float*)(ws + 51904512);

    k_conv_x<<<16384, 256, 0, stream>>>(x, xt);
    k_conv_w<<<dim3(16, 4, 3), 256, 0, stream>>>(Wq, Wk, Wv, Wt);
    k_kv_fused<<<512, 512, 0, stream>>>(xt, Wt, bk, bv, KVb, Ksum);
    k_out_fused<<<dim3(512, 8), 256, 0, stream>>>(xt, Wt, bq, KVb, Ksum, out);
}